// Round 13
// baseline (94.336 us; speedup 1.0000x reference)
//
#include <hip/hip_runtime.h>
#include <math.h>

#define BB 2
#define NN 384
#define DD 256
#define HH 8
#define RN (BB * NN)   // 768
#define INV_SQRT_HD 0.17677669529663687f   // 1/sqrt(32)
#define LOG2E 1.4426950408889634f
#define NLN2 -0.6931471805599453f
#define QSCALE (INV_SQRT_HD * LOG2E)

#define W2_ST 264   // bf16 stride, rb_w2 rows in LDS
#define EB 200      // bf16 stride, staged LDS rows (400B = 100 words; 100%32=4 -> 2-way free)

typedef float f32x4 __attribute__((ext_vector_type(4)));
typedef __bf16 bf16x8 __attribute__((ext_vector_type(8)));
typedef __bf16 bf16x4 __attribute__((ext_vector_type(4)));

__device__ __forceinline__ f32x4 mfma16(bf16x8 a, bf16x8 b, f32x4 c) {
    return __builtin_amdgcn_mfma_f32_16x16x32_bf16(a, b, c, 0, 0, 0);
}

// d = av' - ap' (primes pre-scaled by log2e) = -x*log2e.
// returns -log2e*silu(x); folds: k2a w2bf=-rb_w2; k2c Ts *= -ln2.
__device__ __forceinline__ float hidp(float d) {
    float e = __builtin_amdgcn_exp2f(d);
    return d * __builtin_amdgcn_rcpf(1.0f + e);
}
__device__ __forceinline__ bf16x8 hid8(bf16x8 av, float4 a0, float4 a1) {
    bf16x8 r;
    r[0] = (__bf16)hidp((float)av[0] - a0.x);
    r[1] = (__bf16)hidp((float)av[1] - a0.y);
    r[2] = (__bf16)hidp((float)av[2] - a0.z);
    r[3] = (__bf16)hidp((float)av[3] - a0.w);
    r[4] = (__bf16)hidp((float)av[4] - a1.x);
    r[5] = (__bf16)hidp((float)av[5] - a1.y);
    r[6] = (__bf16)hidp((float)av[6] - a1.z);
    r[7] = (__bf16)hidp((float)av[7] - a1.w);
    return r;
}
__device__ __forceinline__ bf16x8 hid8s(bf16x8 av, float a) {
    bf16x8 r;
#pragma unroll
    for (int q = 0; q < 8; ++q) r[q] = (__bf16)hidp((float)av[q] - a);
    return r;
}
__device__ __forceinline__ bf16x8 pack8(float4 a, float4 b) {
    bf16x8 r;
    r[0] = (__bf16)a.x; r[1] = (__bf16)a.y; r[2] = (__bf16)a.z; r[3] = (__bf16)a.w;
    r[4] = (__bf16)b.x; r[5] = (__bf16)b.y; r[6] = (__bf16)b.z; r[7] = (__bf16)b.w;
    return r;
}
__device__ __forceinline__ float selv(f32x4 v, int r) {
    return (r == 0) ? v[0] : (r == 1) ? v[1] : (r == 2) ? v[2] : v[3];
}

// ---------------- Kernel 1: fused prep ----------------
// [0,576): qkv MFMA. [576,1344): A-arrays (Arb, ArvT, Arv). [1344]: w2neg.
__global__ __launch_bounds__(256) void prep_kernel(
    const float* __restrict__ x, const float* __restrict__ coords,
    const float* __restrict__ qkv_w, const float* __restrict__ qkv_b,
    const float* __restrict__ rb_w1, const float* __restrict__ rv_w1,
    const float* __restrict__ rb_w2,
    float* __restrict__ qb, __bf16* __restrict__ kbbf, __bf16* __restrict__ vT,
    __bf16* __restrict__ Arb, __bf16* __restrict__ ArvT, __bf16* __restrict__ Arv,
    __bf16* __restrict__ w2neg)
{
    int bid = blockIdx.x, tid = threadIdx.x;
    if (bid >= 1344) {
        int idx = tid * 8;
        float4 wa = *(const float4*)(rb_w2 + idx);
        float4 wb = *(const float4*)(rb_w2 + idx + 4);
        float4 na = make_float4(-wa.x, -wa.y, -wa.z, -wa.w);
        float4 nb = make_float4(-wb.x, -wb.y, -wb.z, -wb.w);
        *(bf16x8*)(w2neg + idx) = pack8(na, nb);
        return;
    }
    if (bid >= 576) {
        int r = bid - 576, c = tid;
        float cx = coords[r * 3 + 0], cy = coords[r * 3 + 1], cz = coords[r * 3 + 2];
        float ab = (cx * rb_w1[c * 3] + cy * rb_w1[c * 3 + 1] + cz * rb_w1[c * 3 + 2]) * LOG2E;
        float av = (cx * rv_w1[c * 3] + cy * rv_w1[c * 3 + 1] + cz * rv_w1[c * 3 + 2]) * LOG2E;
        Arb[r * DD + c] = (__bf16)ab;
        ArvT[c * RN + r] = (__bf16)av;
        Arv[r * DD + c] = (__bf16)av;
        return;
    }
    int mt = bid % 48, nb = bid / 48;
    int w = tid >> 6, l = tid & 63, lr = l & 15, lg = l >> 4;
    int m0 = mt * 16, n0 = nb * 64 + w * 16;
    const float* xr = x + (size_t)(m0 + lr) * DD;
    const float* wr = qkv_w + (size_t)(n0 + lr) * DD;
    f32x4 acc = {0.f, 0.f, 0.f, 0.f};
#pragma unroll
    for (int ks = 0; ks < 8; ++ks) {
        int c0 = ks * 32 + lg * 8;
        float4 xa = *(const float4*)(xr + c0);
        float4 xb = *(const float4*)(xr + c0 + 4);
        float4 wa = *(const float4*)(wr + c0);
        float4 wb = *(const float4*)(wr + c0 + 4);
        acc = mfma16(pack8(xa, xb), pack8(wa, wb), acc);
    }
    int col = n0 + lr;
    float bo = qkv_b[col];
    int part = col >> 8, o = col & 255;
#pragma unroll
    for (int r = 0; r < 4; ++r) {
        int m = m0 + lg * 4 + r;
        float v = acc[r] + bo;
        if (part == 0) {
            qb[(size_t)m * DD + o] = v * QSCALE;
        } else if (part == 1) {
            kbbf[(size_t)m * DD + o] = (__bf16)v;
        } else {
            int b = (m >= NN) ? 1 : 0;
            int n = m - b * NN;
            vT[(size_t)b * DD * NN + (size_t)o * NN + n] = (__bf16)v;
        }
    }
}

// ---------------- Kernel 2a: scores + e, gi-PAIR per block (round-11 proven) ----------------
// grid = 768 (384 pairs x 2 j-halves), 256 thr.
__global__ __launch_bounds__(256, 4) void k2a_kernel(
    const float* __restrict__ rb_b1, const __bf16* __restrict__ w2neg,
    const float* __restrict__ rb_b2,
    const float* __restrict__ qb, const __bf16* __restrict__ kbbf,
    const __bf16* __restrict__ Arb,
    __bf16* __restrict__ eG, float* __restrict__ Zpart)
{
    __shared__ __align__(16) __bf16 qsbf[2][DD];
    __shared__ __align__(16) float Apr[2][DD];
    __shared__ __align__(16) __bf16 w2bf[HH * W2_ST];
    __shared__ float redsm[4][2][HH];

    int tid = threadIdx.x;
    int bid = blockIdx.x;
    int gp = bid >> 1, half = bid & 1;
    int gi0 = gp * 2;
    int b = (gp >= 192) ? 1 : 0;

    qsbf[0][tid] = (__bf16)qb[(size_t)gi0 * DD + tid];
    qsbf[1][tid] = (__bf16)qb[(size_t)(gi0 + 1) * DD + tid];
    float b1l = rb_b1[tid] * LOG2E;
    Apr[0][tid] = (float)Arb[(size_t)gi0 * DD + tid] + b1l;
    Apr[1][tid] = (float)Arb[(size_t)(gi0 + 1) * DD + tid] + b1l;
    {
        int idx = tid * 8;
        *(bf16x8*)&w2bf[(idx >> 8) * W2_ST + (idx & 255)] =
            *(const bf16x8*)(w2neg + idx);
    }
    __syncthreads();

    int l = tid & 63, wv = tid >> 6;
    int lr = l & 15, lg = l >> 4;
    float rb2l = rb_b2[lr & 7] * LOG2E;

    int jb0 = half * 192 + wv * 16;
    int jb1 = jb0 + 64, jb2 = jb0 + 128;
    const __bf16* arbB = Arb + (size_t)b * NN * DD;
    const __bf16* kbB  = kbbf + (size_t)b * NN * DD;
    const __bf16* ar0 = arbB + (size_t)(jb0 + lr) * DD;
    const __bf16* ar1 = arbB + (size_t)(jb1 + lr) * DD;
    const __bf16* ar2 = arbB + (size_t)(jb2 + lr) * DD;
    const __bf16* kr0 = kbB  + (size_t)(jb0 + lr) * DD;
    const __bf16* kr1 = kbB  + (size_t)(jb1 + lr) * DD;
    const __bf16* kr2 = kbB  + (size_t)(jb2 + lr) * DD;
    const __bf16* wfp = &w2bf[(lr & 7) * W2_ST];

    bf16x8 qf0_reg = *(const bf16x8*)&qsbf[0][(lr & 7) * 32 + lg * 8];
    bf16x8 qf1_reg = *(const bf16x8*)&qsbf[1][(lr & 7) * 32 + lg * 8];
    bf16x8 zero8;
#pragma unroll
    for (int e = 0; e < 8; ++e) zero8[e] = (__bf16)0.f;

    f32x4 zzz = {0.f, 0.f, 0.f, 0.f};
    f32x4 a00 = zzz, a01 = zzz, a02 = zzz;   // gi0
    f32x4 a10 = zzz, a11 = zzz, a12 = zzz;   // gi1
#pragma unroll
    for (int ks = 0; ks < 8; ++ks) {
        int c0 = ks * 32 + lg * 8;
        bf16x8 v0 = *(const bf16x8*)(ar0 + c0);
        bf16x8 v1 = *(const bf16x8*)(ar1 + c0);
        bf16x8 v2 = *(const bf16x8*)(ar2 + c0);
        bf16x8 k0 = *(const bf16x8*)(kr0 + c0);
        bf16x8 k1 = *(const bf16x8*)(kr1 + c0);
        bf16x8 k2 = *(const bf16x8*)(kr2 + c0);
        bf16x8 wf = *(const bf16x8*)(wfp + c0);
        float4 p00 = *(const float4*)&Apr[0][c0];
        float4 p01 = *(const float4*)&Apr[0][c0 + 4];
        float4 p10 = *(const float4*)&Apr[1][c0];
        float4 p11 = *(const float4*)&Apr[1][c0 + 4];
        bf16x8 q0 = (lr == ks) ? qf0_reg : zero8;
        bf16x8 q1 = (lr == ks) ? qf1_reg : zero8;
        a00 = mfma16(hid8(v0, p00, p01), wf, a00);
        a10 = mfma16(hid8(v0, p10, p11), wf, a10);
        a01 = mfma16(hid8(v1, p00, p01), wf, a01);
        a11 = mfma16(hid8(v1, p10, p11), wf, a11);
        a02 = mfma16(hid8(v2, p00, p01), wf, a02);
        a12 = mfma16(hid8(v2, p10, p11), wf, a12);
        a00 = mfma16(k0, q0, a00);
        a10 = mfma16(k0, q1, a10);
        a01 = mfma16(k1, q0, a01);
        a11 = mfma16(k1, q1, a11);
        a02 = mfma16(k2, q0, a02);
        a12 = mfma16(k2, q1, a12);
    }

    float z0 = 0.f, z1 = 0.f;
#define FINTILE(ACC, GI, JB, ZACC) { \
        float e0 = __builtin_amdgcn_exp2f(ACC[0] + rb2l); \
        float e1 = __builtin_amdgcn_exp2f(ACC[1] + rb2l); \
        float e2 = __builtin_amdgcn_exp2f(ACC[2] + rb2l); \
        float e3 = __builtin_amdgcn_exp2f(ACC[3] + rb2l); \
        if (lr < 8) { \
            bf16x4 ev; \
            ev[0] = (__bf16)e0; ev[1] = (__bf16)e1; \
            ev[2] = (__bf16)e2; ev[3] = (__bf16)e3; \
            *(bf16x4*)&eG[((size_t)(GI) * HH + lr) * NN + (JB) + lg * 4] = ev; \
        } \
        float zs = e0 + e1 + e2 + e3; \
        zs += __shfl_xor(zs, 16); \
        zs += __shfl_xor(zs, 32); \
        ZACC += zs; }
    FINTILE(a00, gi0,     jb0, z0)
    FINTILE(a01, gi0,     jb1, z0)
    FINTILE(a02, gi0,     jb2, z0)
    FINTILE(a10, gi0 + 1, jb0, z1)
    FINTILE(a11, gi0 + 1, jb1, z1)
    FINTILE(a12, gi0 + 1, jb2, z1)
#undef FINTILE
    if (lg == 0 && lr < 8) {
        redsm[wv][0][lr] = z0;
        redsm[wv][1][lr] = z1;
    }
    __syncthreads();
    if (tid < 16) {
        int g = tid >> 3, h = tid & 7;
        Zpart[((size_t)(gi0 + g) * 2 + half) * 8 + h] =
            redsm[0][g][h] + redsm[1][g][h] + redsm[2][g][h] + redsm[3][g][h];
    }
}

// ---------------- Kernel 2b: T/base via LDS-staged streams ----------------
// grid = 3072 (384 pairs x 4 c-quarters x 2 j-halves), 256 thr.
// All inner-loop operands come from LDS (coalesced block staging, 400B rows).
__global__ __launch_bounds__(256, 2) void k2b_kernel(
    const float* __restrict__ rv_b1,
    const __bf16* __restrict__ vT, const __bf16* __restrict__ ArvT,
    const __bf16* __restrict__ Arv, const __bf16* __restrict__ eG,
    __bf16* __restrict__ Tpart, float* __restrict__ basef)
{
    __shared__ __align__(16) __bf16 AvL[64 * EB];   // 25.6 KB
    __shared__ __align__(16) __bf16 VtL[64 * EB];   // 25.6 KB
    __shared__ __align__(16) __bf16 EL[16 * EB];    // 6.4 KB
    __shared__ float aps[2][64];

    int tid = threadIdx.x;
    int bid = blockIdx.x;
    int gp = bid >> 3, cq = (bid >> 1) & 3, jh = bid & 1;
    int gi0 = gp * 2;
    int b = (gp >= 192) ? 1 : 0;
    int joff = b * NN + jh * 192;

    const __bf16* avbase = ArvT + (size_t)(cq * 64) * RN + joff;                      // +r*RN
    const __bf16* vtbase = vT + (size_t)b * DD * NN + (size_t)(cq * 64) * NN + jh * 192;  // +r*NN
    const __bf16* ebase  = eG + (size_t)(gi0 * 8) * NN + jh * 192;                    // +r*NN

    // coalesced staging: 24 16B-chunks per 384B row; loads batched before writes
    bf16x8 tA[6], tV[6], tE0, tE1;
#pragma unroll
    for (int s = 0; s < 6; ++s) {
        int idx = tid + s * 256;
        int r = idx / 24, cc = idx - r * 24;
        tA[s] = *(const bf16x8*)(avbase + (size_t)r * RN + cc * 8);
        tV[s] = *(const bf16x8*)(vtbase + (size_t)r * NN + cc * 8);
    }
    {
        int r = tid / 24, cc = tid - r * 24;
        tE0 = *(const bf16x8*)(ebase + (size_t)r * NN + cc * 8);
        if (tid < 128) {
            int idx = 256 + tid;
            int r1 = idx / 24, cc1 = idx - r1 * 24;
            tE1 = *(const bf16x8*)(ebase + (size_t)r1 * NN + cc1 * 8);
        }
    }
    if (tid < 128) {
        int g = tid >> 6, c = tid & 63;
        aps[g][c] = (float)Arv[(size_t)(gi0 + g) * DD + cq * 64 + c]
                  + rv_b1[cq * 64 + c] * LOG2E;
    }
#pragma unroll
    for (int s = 0; s < 6; ++s) {
        int idx = tid + s * 256;
        int r = idx / 24, cc = idx - r * 24;
        *(bf16x8*)&AvL[r * EB + cc * 8] = tA[s];
        *(bf16x8*)&VtL[r * EB + cc * 8] = tV[s];
    }
    {
        int r = tid / 24, cc = tid - r * 24;
        *(bf16x8*)&EL[r * EB + cc * 8] = tE0;
        if (tid < 128) {
            int idx = 256 + tid;
            int r1 = idx / 24, cc1 = idx - r1 * 24;
            *(bf16x8*)&EL[r1 * EB + cc1 * 8] = tE1;
        }
    }
    __syncthreads();

    int l = tid & 63, wv = tid >> 6;
    int lr = l & 15, lg = l >> 4;
    int rc_ = wv * 16 + lr;                 // c-local 0..63
    float ap0 = aps[0][rc_], ap1 = aps[1][rc_];

    f32x4 zz = {0.f, 0.f, 0.f, 0.f};
    f32x4 T0 = zz, T1 = zz, B0 = zz;
#pragma unroll
    for (int ks = 0; ks < 6; ++ks) {
        int jo = ks * 32 + lg * 8;
        bf16x8 ef  = *(const bf16x8*)&EL[lr * EB + jo];
        bf16x8 av  = *(const bf16x8*)&AvL[rc_ * EB + jo];
        bf16x8 wv8 = *(const bf16x8*)&VtL[rc_ * EB + jo];
        T0 = mfma16(ef, hid8s(av, ap0), T0);   // valid D rows 0-7  (gi0)
        T1 = mfma16(ef, hid8s(av, ap1), T1);   // valid D rows 8-15 (gi1)
        B0 = mfma16(ef, wv8, B0);              // packed: rows 0-7 gi0, 8-15 gi1
    }

    int cglob = cq * 64 + rc_;
    __bf16* tp = Tpart + (size_t)jh * RN * HH * DD;
    if (lg < 2) {
#pragma unroll
        for (int r = 0; r < 4; ++r) {
            int h = lg * 4 + r;
            tp[((size_t)gi0 * HH + h) * DD + cglob] = (__bf16)T0[r];
        }
    } else {
#pragma unroll
        for (int r = 0; r < 4; ++r) {
            int h = (lg - 2) * 4 + r;
            tp[((size_t)(gi0 + 1) * HH + h) * DD + cglob] = (__bf16)T1[r];
        }
    }
    {
        int h = cglob >> 5;   // 0..7, wave-uniform
        float* bz = basef + (size_t)jh * RN * DD;
        if (lg == (h >> 2))     bz[(size_t)gi0 * DD + cglob]       = selv(B0, h & 3);
        if (lg == 2 + (h >> 2)) bz[(size_t)(gi0 + 1) * DD + cglob] = selv(B0, h & 3);
    }
}

// ---------------- Kernel 2c: sum T partials, rc dot, combine. grid = 768 ----------------
__global__ __launch_bounds__(256) void k2c_kernel(
    const __bf16* __restrict__ Tpart, const float* __restrict__ basef,
    const float* __restrict__ Zpart, const float* __restrict__ rv_w2,
    const float* __restrict__ rv_b2, float* __restrict__ out)
{
    __shared__ __align__(16) float Ts[HH * 264];
    int gi = blockIdx.x, tid = threadIdx.x;
    const __bf16* t0 = Tpart + (size_t)gi * HH * DD;
    const __bf16* t1 = Tpart + ((size_t)RN + gi) * HH * DD;
    {
        int h = tid >> 5, c0 = (tid & 31) * 8;
        bf16x8 u0 = *(const bf16x8*)&t0[h * DD + c0];
        bf16x8 u1 = *(const bf16x8*)&t1[h * DD + c0];
#pragma unroll
        for (int q = 0; q < 8; ++q)
            Ts[h * 264 + c0 + q] = ((float)u0[q] + (float)u1[q]) * NLN2;
    }
    __syncthreads();

    int o = tid, h = o >> 5;
    float z = Zpart[(size_t)gi * 16 + h] + Zpart[(size_t)gi * 16 + 8 + h];
    const float4* w2p = (const float4*)(rv_w2 + (size_t)o * DD);
    const float* trow = &Ts[h * 264];
    float a = 0.f;
#pragma unroll 4
    for (int cc = 0; cc < 64; ++cc) {
        float4 w4 = w2p[cc];
        float4 u = *(const float4*)&trow[cc * 4];
        a += w4.x * u.x + w4.y * u.y + w4.z * u.z + w4.w * u.w;
    }
    size_t io = (size_t)gi * DD + o;
    const size_t SL = (size_t)RN * DD;
    float base = basef[io] + basef[SL + io];
    out[io] = (a + base) * __builtin_amdgcn_rcpf(z) + rv_b2[o];
}

extern "C" void kernel_launch(void* const* d_in, const int* in_sizes, int n_in,
                              void* d_out, int out_size, void* d_ws, size_t ws_size,
                              hipStream_t stream) {
    const float* x      = (const float*)d_in[0];
    const float* coords = (const float*)d_in[1];
    const float* qkv_w  = (const float*)d_in[2];
    const float* qkv_b  = (const float*)d_in[3];
    const float* rb_w1  = (const float*)d_in[4];
    const float* rb_b1  = (const float*)d_in[5];
    const float* rb_w2  = (const float*)d_in[6];
    const float* rb_b2  = (const float*)d_in[7];
    const float* rv_w1  = (const float*)d_in[8];
    const float* rv_b1  = (const float*)d_in[9];
    const float* rv_w2  = (const float*)d_in[10];
    const float* rv_b2  = (const float*)d_in[11];
    float* out = (float*)d_out;

    float* ws = (float*)d_ws;
    const int PER = RN * DD;               // 196608
    float* qb = ws;                        // PER f32
    __bf16* bfb  = (__bf16*)(ws + PER);
    __bf16* kbbf = bfb;                    // PER bf16
    __bf16* vTb  = bfb + PER;              // PER bf16
    __bf16* Arb  = bfb + 2 * PER;          // PER bf16
    __bf16* ArvT = bfb + 3 * PER;          // PER bf16
    __bf16* Arv  = bfb + 4 * PER;          // PER bf16
    __bf16* eG   = bfb + 5 * (size_t)PER;             // RN*HH*NN bf16
    __bf16* Tpart = eG + (size_t)RN * HH * NN;         // 2*RN*HH*DD bf16
    float* Zpart = (float*)(Tpart + (size_t)2 * RN * HH * DD);  // RN*2*HH f32
    float* basef = Zpart + (size_t)RN * 2 * HH;        // 2*PER f32
    __bf16* w2neg = (__bf16*)(basef + 2 * (size_t)PER);  // 2048 bf16

    prep_kernel<<<1345, 256, 0, stream>>>(x, coords, qkv_w, qkv_b,
                                          rb_w1, rv_w1, rb_w2,
                                          qb, kbbf, vTb, Arb, ArvT, Arv, w2neg);
    k2a_kernel<<<RN, 256, 0, stream>>>(rb_b1, w2neg, rb_b2,
                                       qb, kbbf, Arb, eG, Zpart);
    k2b_kernel<<<8 * 384, 256, 0, stream>>>(rv_b1, vTb, ArvT, Arv, eG,
                                            Tpart, basef);
    k2c_kernel<<<RN, 256, 0, stream>>>(Tpart, basef, Zpart, rv_w2, rv_b2, out);
}

// Round 14
// 75.806 us; speedup vs baseline: 1.2444x; 1.2444x over previous
//
#include <hip/hip_runtime.h>
#include <math.h>

#define BB 2
#define NN 384
#define DD 256
#define HH 8
#define RN (BB * NN)   // 768
#define INV_SQRT_HD 0.17677669529663687f   // 1/sqrt(32)
#define LOG2E 1.4426950408889634f
#define NLN2 -0.6931471805599453f
#define QSCALE (INV_SQRT_HD * LOG2E)

#define W2_ST 264   // bf16 stride, rb_w2 rows in LDS
#define T_ST  264   // f32 stride, T rows
#define EB_ST 392   // bf16 stride, staged e rows

typedef float f32x4 __attribute__((ext_vector_type(4)));
typedef __bf16 bf16x8 __attribute__((ext_vector_type(8)));
typedef __bf16 bf16x4 __attribute__((ext_vector_type(4)));

__device__ __forceinline__ f32x4 mfma16(bf16x8 a, bf16x8 b, f32x4 c) {
    return __builtin_amdgcn_mfma_f32_16x16x32_bf16(a, b, c, 0, 0, 0);
}

// d = av' - ap' (primes pre-scaled by log2e) = -x*log2e.
// returns -log2e*silu(x); folds: k2a w2bf=-rb_w2; k2b Tl *= -ln2.
__device__ __forceinline__ float hidp(float d) {
    float e = __builtin_amdgcn_exp2f(d);
    return d * __builtin_amdgcn_rcpf(1.0f + e);
}
__device__ __forceinline__ bf16x8 hid8(bf16x8 av, float4 a0, float4 a1) {
    bf16x8 r;
    r[0] = (__bf16)hidp((float)av[0] - a0.x);
    r[1] = (__bf16)hidp((float)av[1] - a0.y);
    r[2] = (__bf16)hidp((float)av[2] - a0.z);
    r[3] = (__bf16)hidp((float)av[3] - a0.w);
    r[4] = (__bf16)hidp((float)av[4] - a1.x);
    r[5] = (__bf16)hidp((float)av[5] - a1.y);
    r[6] = (__bf16)hidp((float)av[6] - a1.z);
    r[7] = (__bf16)hidp((float)av[7] - a1.w);
    return r;
}
__device__ __forceinline__ bf16x8 hid8s(bf16x8 av, float a) {
    bf16x8 r;
#pragma unroll
    for (int q = 0; q < 8; ++q) r[q] = (__bf16)hidp((float)av[q] - a);
    return r;
}
__device__ __forceinline__ bf16x8 pack8(float4 a, float4 b) {
    bf16x8 r;
    r[0] = (__bf16)a.x; r[1] = (__bf16)a.y; r[2] = (__bf16)a.z; r[3] = (__bf16)a.w;
    r[4] = (__bf16)b.x; r[5] = (__bf16)b.y; r[6] = (__bf16)b.z; r[7] = (__bf16)b.w;
    return r;
}
__device__ __forceinline__ float selv(f32x4 v, int r) {
    return (r == 0) ? v[0] : (r == 1) ? v[1] : (r == 2) ? v[2] : v[3];
}

// ---------------- Kernel 1: fused prep ----------------
// [0,576): qkv MFMA. [576,1344): A-arrays (Arb, ArvT, Arv). [1344]: w2neg.
__global__ __launch_bounds__(256) void prep_kernel(
    const float* __restrict__ x, const float* __restrict__ coords,
    const float* __restrict__ qkv_w, const float* __restrict__ qkv_b,
    const float* __restrict__ rb_w1, const float* __restrict__ rv_w1,
    const float* __restrict__ rb_w2,
    float* __restrict__ qb, __bf16* __restrict__ kbbf, __bf16* __restrict__ vT,
    __bf16* __restrict__ Arb, __bf16* __restrict__ ArvT, __bf16* __restrict__ Arv,
    __bf16* __restrict__ w2neg)
{
    int bid = blockIdx.x, tid = threadIdx.x;
    if (bid >= 1344) {
        int idx = tid * 8;
        float4 wa = *(const float4*)(rb_w2 + idx);
        float4 wb = *(const float4*)(rb_w2 + idx + 4);
        float4 na = make_float4(-wa.x, -wa.y, -wa.z, -wa.w);
        float4 nb = make_float4(-wb.x, -wb.y, -wb.z, -wb.w);
        *(bf16x8*)(w2neg + idx) = pack8(na, nb);
        return;
    }
    if (bid >= 576) {
        int r = bid - 576, c = tid;
        float cx = coords[r * 3 + 0], cy = coords[r * 3 + 1], cz = coords[r * 3 + 2];
        float ab = (cx * rb_w1[c * 3] + cy * rb_w1[c * 3 + 1] + cz * rb_w1[c * 3 + 2]) * LOG2E;
        float av = (cx * rv_w1[c * 3] + cy * rv_w1[c * 3 + 1] + cz * rv_w1[c * 3 + 2]) * LOG2E;
        Arb[r * DD + c] = (__bf16)ab;
        ArvT[c * RN + r] = (__bf16)av;
        Arv[r * DD + c] = (__bf16)av;
        return;
    }
    int mt = bid % 48, nb = bid / 48;
    int w = tid >> 6, l = tid & 63, lr = l & 15, lg = l >> 4;
    int m0 = mt * 16, n0 = nb * 64 + w * 16;
    const float* xr = x + (size_t)(m0 + lr) * DD;
    const float* wr = qkv_w + (size_t)(n0 + lr) * DD;
    f32x4 acc = {0.f, 0.f, 0.f, 0.f};
#pragma unroll
    for (int ks = 0; ks < 8; ++ks) {
        int c0 = ks * 32 + lg * 8;
        float4 xa = *(const float4*)(xr + c0);
        float4 xb = *(const float4*)(xr + c0 + 4);
        float4 wa = *(const float4*)(wr + c0);
        float4 wb = *(const float4*)(wr + c0 + 4);
        acc = mfma16(pack8(xa, xb), pack8(wa, wb), acc);
    }
    int col = n0 + lr;
    float bo = qkv_b[col];
    int part = col >> 8, o = col & 255;
#pragma unroll
    for (int r = 0; r < 4; ++r) {
        int m = m0 + lg * 4 + r;
        float v = acc[r] + bo;
        if (part == 0) {
            qb[(size_t)m * DD + o] = v * QSCALE;
        } else if (part == 1) {
            kbbf[(size_t)m * DD + o] = (__bf16)v;
        } else {
            int b = (m >= NN) ? 1 : 0;
            int n = m - b * NN;
            vT[(size_t)b * DD * NN + (size_t)o * NN + n] = (__bf16)v;
        }
    }
}

// ---------------- Kernel 2a: scores + e, gi-PAIR per block ----------------
// grid = 768 (384 pairs x 2 j-halves), 256 thr. ar/k streams shared across pair.
__global__ __launch_bounds__(256, 4) void k2a_kernel(
    const float* __restrict__ rb_b1, const __bf16* __restrict__ w2neg,
    const float* __restrict__ rb_b2,
    const float* __restrict__ qb, const __bf16* __restrict__ kbbf,
    const __bf16* __restrict__ Arb,
    __bf16* __restrict__ eG, float* __restrict__ Zpart)
{
    __shared__ __align__(16) __bf16 qsbf[2][DD];
    __shared__ __align__(16) float Apr[2][DD];
    __shared__ __align__(16) __bf16 w2bf[HH * W2_ST];
    __shared__ float redsm[4][2][HH];

    int tid = threadIdx.x;
    int bid = blockIdx.x;
    int gp = bid >> 1, half = bid & 1;
    int gi0 = gp * 2;
    int b = (gp >= 192) ? 1 : 0;

    qsbf[0][tid] = (__bf16)qb[(size_t)gi0 * DD + tid];
    qsbf[1][tid] = (__bf16)qb[(size_t)(gi0 + 1) * DD + tid];
    float b1l = rb_b1[tid] * LOG2E;
    Apr[0][tid] = (float)Arb[(size_t)gi0 * DD + tid] + b1l;
    Apr[1][tid] = (float)Arb[(size_t)(gi0 + 1) * DD + tid] + b1l;
    {
        int idx = tid * 8;
        *(bf16x8*)&w2bf[(idx >> 8) * W2_ST + (idx & 255)] =
            *(const bf16x8*)(w2neg + idx);
    }
    __syncthreads();

    int l = tid & 63, wv = tid >> 6;
    int lr = l & 15, lg = l >> 4;
    float rb2l = rb_b2[lr & 7] * LOG2E;

    int jb0 = half * 192 + wv * 16;
    int jb1 = jb0 + 64, jb2 = jb0 + 128;
    const __bf16* arbB = Arb + (size_t)b * NN * DD;
    const __bf16* kbB  = kbbf + (size_t)b * NN * DD;
    const __bf16* ar0 = arbB + (size_t)(jb0 + lr) * DD;
    const __bf16* ar1 = arbB + (size_t)(jb1 + lr) * DD;
    const __bf16* ar2 = arbB + (size_t)(jb2 + lr) * DD;
    const __bf16* kr0 = kbB  + (size_t)(jb0 + lr) * DD;
    const __bf16* kr1 = kbB  + (size_t)(jb1 + lr) * DD;
    const __bf16* kr2 = kbB  + (size_t)(jb2 + lr) * DD;
    const __bf16* wfp = &w2bf[(lr & 7) * W2_ST];

    bf16x8 qf0_reg = *(const bf16x8*)&qsbf[0][(lr & 7) * 32 + lg * 8];
    bf16x8 qf1_reg = *(const bf16x8*)&qsbf[1][(lr & 7) * 32 + lg * 8];
    bf16x8 zero8;
#pragma unroll
    for (int e = 0; e < 8; ++e) zero8[e] = (__bf16)0.f;

    f32x4 zzz = {0.f, 0.f, 0.f, 0.f};
    f32x4 a00 = zzz, a01 = zzz, a02 = zzz;   // gi0
    f32x4 a10 = zzz, a11 = zzz, a12 = zzz;   // gi1
#pragma unroll
    for (int ks = 0; ks < 8; ++ks) {
        int c0 = ks * 32 + lg * 8;
        bf16x8 v0 = *(const bf16x8*)(ar0 + c0);
        bf16x8 v1 = *(const bf16x8*)(ar1 + c0);
        bf16x8 v2 = *(const bf16x8*)(ar2 + c0);
        bf16x8 k0 = *(const bf16x8*)(kr0 + c0);
        bf16x8 k1 = *(const bf16x8*)(kr1 + c0);
        bf16x8 k2 = *(const bf16x8*)(kr2 + c0);
        bf16x8 wf = *(const bf16x8*)(wfp + c0);
        float4 p00 = *(const float4*)&Apr[0][c0];
        float4 p01 = *(const float4*)&Apr[0][c0 + 4];
        float4 p10 = *(const float4*)&Apr[1][c0];
        float4 p11 = *(const float4*)&Apr[1][c0 + 4];
        bf16x8 q0 = (lr == ks) ? qf0_reg : zero8;
        bf16x8 q1 = (lr == ks) ? qf1_reg : zero8;
        a00 = mfma16(hid8(v0, p00, p01), wf, a00);
        a10 = mfma16(hid8(v0, p10, p11), wf, a10);
        a01 = mfma16(hid8(v1, p00, p01), wf, a01);
        a11 = mfma16(hid8(v1, p10, p11), wf, a11);
        a02 = mfma16(hid8(v2, p00, p01), wf, a02);
        a12 = mfma16(hid8(v2, p10, p11), wf, a12);
        a00 = mfma16(k0, q0, a00);
        a10 = mfma16(k0, q1, a10);
        a01 = mfma16(k1, q0, a01);
        a11 = mfma16(k1, q1, a11);
        a02 = mfma16(k2, q0, a02);
        a12 = mfma16(k2, q1, a12);
    }

    float z0 = 0.f, z1 = 0.f;
#define FINTILE(ACC, GI, JB, ZACC) { \
        float e0 = __builtin_amdgcn_exp2f(ACC[0] + rb2l); \
        float e1 = __builtin_amdgcn_exp2f(ACC[1] + rb2l); \
        float e2 = __builtin_amdgcn_exp2f(ACC[2] + rb2l); \
        float e3 = __builtin_amdgcn_exp2f(ACC[3] + rb2l); \
        if (lr < 8) { \
            bf16x4 ev; \
            ev[0] = (__bf16)e0; ev[1] = (__bf16)e1; \
            ev[2] = (__bf16)e2; ev[3] = (__bf16)e3; \
            *(bf16x4*)&eG[((size_t)(GI) * HH + lr) * NN + (JB) + lg * 4] = ev; \
        } \
        float zs = e0 + e1 + e2 + e3; \
        zs += __shfl_xor(zs, 16); \
        zs += __shfl_xor(zs, 32); \
        ZACC += zs; }
    FINTILE(a00, gi0,     jb0, z0)
    FINTILE(a01, gi0,     jb1, z0)
    FINTILE(a02, gi0,     jb2, z0)
    FINTILE(a10, gi0 + 1, jb0, z1)
    FINTILE(a11, gi0 + 1, jb1, z1)
    FINTILE(a12, gi0 + 1, jb2, z1)
#undef FINTILE
    if (lg == 0 && lr < 8) {
        redsm[wv][0][lr] = z0;
        redsm[wv][1][lr] = z1;
    }
    __syncthreads();
    if (tid < 16) {
        int g = tid >> 3, h = tid & 7;
        Zpart[((size_t)(gi0 + g) * 2 + half) * 8 + h] =
            redsm[0][g][h] + redsm[1][g][h] + redsm[2][g][h] + redsm[3][g][h];
    }
}

// ---------------- Kernel 2b: T/base, gi-PAIR packed, e staged in LDS ----------------
// grid = 768 (384 pairs x 2 c-halves), 256 thr, 12 K-iters.
__global__ __launch_bounds__(256, 4) void k2b_kernel(
    const float* __restrict__ rv_b1, const float* __restrict__ rv_w2,
    const __bf16* __restrict__ vT, const __bf16* __restrict__ ArvT,
    const __bf16* __restrict__ Arv, const __bf16* __restrict__ eG,
    float* __restrict__ rcpart, float* __restrict__ basef)
{
    __shared__ __align__(16) float Apv[2][DD];
    __shared__ __align__(16) float Tl[2][HH * T_ST];
    __shared__ __align__(16) __bf16 els[16 * EB_ST];

    int tid = threadIdx.x;
    int bid = blockIdx.x;
    int gp = bid >> 1, ch = bid & 1;
    int gi0 = gp * 2;
    int b = (gp >= 192) ? 1 : 0;

    // coalesced Apv setup from row-major Arv (was a 256-line ArvT gather)
    float b1l = rv_b1[tid] * LOG2E;
    Apv[0][tid] = (float)Arv[(size_t)gi0 * DD + tid] + b1l;
    Apv[1][tid] = (float)Arv[(size_t)(gi0 + 1) * DD + tid] + b1l;
    // stage the 16 shared e-rows (rows 0-7: gi0, 8-15: gi1)
    {
        int r = tid >> 4, cg = tid & 15;
        const __bf16* src = eG + (size_t)(gi0 * 8 + r) * NN;
#pragma unroll
        for (int s = 0; s < 3; ++s) {
            int col = s * 128 + cg * 8;
            *(bf16x8*)&els[r * EB_ST + col] = *(const bf16x8*)(src + col);
        }
    }
    __syncthreads();

    int l = tid & 63, wv = tid >> 6;
    int lr = l & 15, lg = l >> 4;

    int c0 = ch * 128 + wv * 16 + lr;
    int c1 = c0 + 64;
    float ap00 = Apv[0][c0], ap01 = Apv[0][c1];
    float ap10 = Apv[1][c0], ap11 = Apv[1][c1];
    const __bf16* vr0 = ArvT + (size_t)c0 * RN + b * NN;
    const __bf16* vr1 = ArvT + (size_t)c1 * RN + b * NN;
    const __bf16* tv0 = vT + (size_t)b * DD * NN + (size_t)c0 * NN;
    const __bf16* tv1 = vT + (size_t)b * DD * NN + (size_t)c1 * NN;

    f32x4 zzz = {0.f, 0.f, 0.f, 0.f};
    f32x4 T00 = zzz, T01 = zzz, T10 = zzz, T11 = zzz;
    f32x4 B0 = zzz, B1 = zzz;
#pragma unroll
    for (int ks = 0; ks < 12; ++ks) {
        int j0 = ks * 32 + lg * 8;
        bf16x8 ef  = *(const bf16x8*)&els[lr * EB_ST + j0];
        bf16x8 av0 = *(const bf16x8*)(vr0 + j0);
        bf16x8 av1 = *(const bf16x8*)(vr1 + j0);
        bf16x8 w0  = *(const bf16x8*)(tv0 + j0);
        bf16x8 w1  = *(const bf16x8*)(tv1 + j0);
        T00 = mfma16(ef, hid8s(av0, ap00), T00);   // valid rows 0-7  (gi0)
        T01 = mfma16(ef, hid8s(av1, ap01), T01);
        T10 = mfma16(ef, hid8s(av0, ap10), T10);   // valid rows 8-15 (gi1)
        T11 = mfma16(ef, hid8s(av1, ap11), T11);
        B0  = mfma16(ef, w0, B0);                  // packed: rows 0-7 gi0, 8-15 gi1
        B1  = mfma16(ef, w1, B1);
    }

    if (lg < 2) {
#pragma unroll
        for (int r = 0; r < 4; ++r) {
            int h = lg * 4 + r;
            Tl[0][h * T_ST + c0] = T00[r] * NLN2;
            Tl[0][h * T_ST + c1] = T01[r] * NLN2;
        }
    } else {
#pragma unroll
        for (int r = 0; r < 4; ++r) {
            int h = (lg - 2) * 4 + r;
            Tl[1][h * T_ST + c0] = T10[r] * NLN2;
            Tl[1][h * T_ST + c1] = T11[r] * NLN2;
        }
    }
    // base: D col c needs row h=c>>5 (gi0) and 8+h (gi1)
    {
        int h0 = c0 >> 5;
        if (lg == (h0 >> 2))     basef[(size_t)gi0 * DD + c0]       = selv(B0, h0 & 3);
        if (lg == 2 + (h0 >> 2)) basef[(size_t)(gi0 + 1) * DD + c0] = selv(B0, h0 & 3);
        int h1 = c1 >> 5;
        if (lg == (h1 >> 2))     basef[(size_t)gi0 * DD + c1]       = selv(B1, h1 & 3);
        if (lg == 2 + (h1 >> 2)) basef[(size_t)(gi0 + 1) * DD + c1] = selv(B1, h1 & 3);
    }
    __syncthreads();

    // rc partial over this c-half: o = tid
    {
        int o = tid, h = o >> 5;
        const float4* w2p = (const float4*)(rv_w2 + (size_t)o * DD);
        const float* t0 = &Tl[0][h * T_ST];
        const float* t1 = &Tl[1][h * T_ST];
        float a0 = 0.f, a1 = 0.f;
#pragma unroll 4
        for (int cc = 0; cc < 32; ++cc) {
            int cidx = ch * 32 + cc;
            float4 wv4 = w2p[cidx];
            float4 u0 = *(const float4*)&t0[cidx * 4];
            float4 u1 = *(const float4*)&t1[cidx * 4];
            a0 += wv4.x * u0.x + wv4.y * u0.y + wv4.z * u0.z + wv4.w * u0.w;
            a1 += wv4.x * u1.x + wv4.y * u1.y + wv4.z * u1.z + wv4.w * u1.w;
        }
        rcpart[((size_t)ch * RN + gi0) * DD + o] = a0;
        rcpart[((size_t)ch * RN + gi0 + 1) * DD + o] = a1;
    }
}

// ---------------- Kernel 2c: combine. grid = 768, 256 thr ----------------
__global__ __launch_bounds__(256) void k2c_kernel(
    const float* __restrict__ rcpart, const float* __restrict__ basef,
    const float* __restrict__ Zpart, const float* __restrict__ rv_b2,
    float* __restrict__ out)
{
    int gi = blockIdx.x, o = threadIdx.x, h = o >> 5;
    float z = Zpart[(size_t)gi * 16 + h] + Zpart[(size_t)gi * 16 + 8 + h];
    float rc = rcpart[(size_t)gi * DD + o] + rcpart[((size_t)RN + gi) * DD + o];
    out[(size_t)gi * DD + o] =
        (rc + basef[(size_t)gi * DD + o]) * __builtin_amdgcn_rcpf(z) + rv_b2[o];
}

extern "C" void kernel_launch(void* const* d_in, const int* in_sizes, int n_in,
                              void* d_out, int out_size, void* d_ws, size_t ws_size,
                              hipStream_t stream) {
    const float* x      = (const float*)d_in[0];
    const float* coords = (const float*)d_in[1];
    const float* qkv_w  = (const float*)d_in[2];
    const float* qkv_b  = (const float*)d_in[3];
    const float* rb_w1  = (const float*)d_in[4];
    const float* rb_b1  = (const float*)d_in[5];
    const float* rb_w2  = (const float*)d_in[6];
    const float* rb_b2  = (const float*)d_in[7];
    const float* rv_w1  = (const float*)d_in[8];
    const float* rv_b1  = (const float*)d_in[9];
    const float* rv_w2  = (const float*)d_in[10];
    const float* rv_b2  = (const float*)d_in[11];
    float* out = (float*)d_out;

    float* ws = (float*)d_ws;
    const int PER = RN * DD;               // 196608
    float* qb = ws;                        // PER f32
    __bf16* bfb  = (__bf16*)(ws + PER);
    __bf16* kbbf = bfb;                    // PER bf16
    __bf16* vTb  = bfb + PER;              // PER bf16
    __bf16* Arb  = bfb + 2 * PER;          // PER bf16
    __bf16* ArvT = bfb + 3 * PER;          // PER bf16
    __bf16* Arv  = bfb + 4 * PER;          // PER bf16 (row-major copy)
    __bf16* eG   = bfb + 5 * (size_t)PER;  // RN*HH*NN bf16
    float* Zpart = (float*)(eG + (size_t)RN * HH * NN);   // RN*2*HH f32
    float* basef = Zpart + (size_t)RN * 2 * HH;           // PER f32
    float* rcpart = basef + PER;                          // 2*PER f32
    __bf16* w2neg = (__bf16*)(rcpart + 2 * (size_t)PER);  // 2048 bf16

    prep_kernel<<<1345, 256, 0, stream>>>(x, coords, qkv_w, qkv_b,
                                          rb_w1, rv_w1, rb_w2,
                                          qb, kbbf, vTb, Arb, ArvT, Arv, w2neg);
    k2a_kernel<<<RN, 256, 0, stream>>>(rb_b1, w2neg, rb_b2,
                                       qb, kbbf, Arb, eG, Zpart);
    k2b_kernel<<<RN, 256, 0, stream>>>(rv_b1, rv_w2,
                                       vTb, ArvT, Arv, eG, rcpart, basef);
    k2c_kernel<<<RN, 256, 0, stream>>>(rcpart, basef, Zpart, rv_b2, out);
}